// Round 3
// baseline (4861.168 us; speedup 1.0000x reference)
//
#include <hip/hip_runtime.h>
#include <math.h>

#define BB   64
#define TT   128
#define HH   1024
#define DIN  2048
#define G4   4096
#define MALL 8192   // B*T
#define NANS 1000

typedef __attribute__((ext_vector_type(8))) short bf16x8;
typedef __attribute__((ext_vector_type(4))) float f32x4;

__device__ __forceinline__ float sigmoidf_(float x) { return 1.0f / (1.0f + expf(-x)); }

__device__ __forceinline__ unsigned short f2bf(float f) {
  unsigned u = __float_as_uint(f);
  u = (u + 0x7fff + ((u >> 16) & 1)) >> 16;   // RNE
  return (unsigned short)u;
}
__device__ __forceinline__ float bf2f(unsigned short h) {
  return __uint_as_float(((unsigned)h) << 16);
}
__device__ __forceinline__ f32x4 mfma16(bf16x8 a, bf16x8 b, f32x4 c) {
  return __builtin_amdgcn_mfma_f32_16x16x32_bf16(a, b, c, 0, 0, 0);
}

// ---------------------------------------------------------------------------
// conversion kernels
// ---------------------------------------------------------------------------
__global__ __launch_bounds__(256) void concat_cast(
    const float* __restrict__ a, const float* __restrict__ b,
    unsigned short* __restrict__ o, int rshift, long total)
{
  long idx = ((long)blockIdx.x * 256 + threadIdx.x) * 4;
  if (idx >= total) return;
  int row = (int)(idx >> rshift);
  int col = (int)(idx & ((1L << rshift) - 1));
  int half = 1 << (rshift - 1);
  const float* s = (col < half) ? (a + (size_t)row * half + col)
                                : (b + (size_t)row * half + col - half);
  float4 v = *(const float4*)s;
  ushort4 ov;
  ov.x = f2bf(v.x); ov.y = f2bf(v.y); ov.z = f2bf(v.z); ov.w = f2bf(v.w);
  *(ushort4*)(o + idx) = ov;
}

__global__ __launch_bounds__(256) void cast_bf16(
    const float* __restrict__ s, unsigned short* __restrict__ o, long n)
{
  long idx = ((long)blockIdx.x * 256 + threadIdx.x) * 4;
  if (idx >= n) return;
  float4 v = *(const float4*)(s + idx);
  ushort4 ov;
  ov.x = f2bf(v.x); ov.y = f2bf(v.y); ov.z = f2bf(v.z); ov.w = f2bf(v.w);
  *(ushort4*)(o + idx) = ov;
}

__global__ __launch_bounds__(256) void cvt_wp1(
    const float* __restrict__ Wp1, unsigned short* __restrict__ o)
{
  int idx = blockIdx.x * 256 + threadIdx.x;    // 262144
  int n = idx >> 10, k = idx & 1023;
  o[idx] = f2bf(Wp1[(size_t)k * 256 + n]);
}

__global__ __launch_bounds__(256) void cvt_wp2(
    const float* __restrict__ Wp2, unsigned short* __restrict__ o)
{
  int idx = blockIdx.x * 256 + threadIdx.x;    // 262144
  int n = idx >> 8, k = idx & 255;
  o[idx] = f2bf(n < NANS ? Wp2[(size_t)k * NANS + n] : 0.f);
}

__global__ __launch_bounds__(256) void zero_hb(
    float4* __restrict__ p, unsigned int* __restrict__ bar)
{
  p[blockIdx.x * 256 + threadIdx.x] = make_float4(0.f, 0.f, 0.f, 0.f);
  if (blockIdx.x == 0 && threadIdx.x == 0) *bar = 0u;
}

// ---------------------------------------------------------------------------
// Templated bf16 MFMA GEMM: C = A @ W^T (+bias)(relu). 128x128 tile, BK=64.
// ---------------------------------------------------------------------------
template<int OUT_BF16, int RELU, int PERM>
__global__ __launch_bounds__(256) void mfma_gemm(
    const unsigned short* __restrict__ A,   // [M][K] bf16
    const unsigned short* __restrict__ W,   // [N][K] bf16
    const float* __restrict__ bias,         // [nvalid]
    void* __restrict__ Cout,
    int M, int N, int K, int ldc, int nvalid)
{
  __shared__ __align__(16) unsigned short As[128 * 72];
  __shared__ __align__(16) unsigned short Bs[128 * 72];
  const int t = threadIdx.x;
  const int n0 = blockIdx.x * 128, m0 = blockIdx.y * 128;
  const int w = t >> 6, lane = t & 63, lr = lane & 15, q = lane >> 4;
  const int wn = (w & 1) * 64, wm = (w >> 1) * 64;
  f32x4 acc[4][4] = {};
  for (int k0 = 0; k0 < K; k0 += 64) {
    #pragma unroll
    for (int s = 0; s < 4; s++) {
      int ci = s * 256 + t;
      int row = ci >> 3, c = ci & 7;
      bf16x8 va = *(const bf16x8*)(A + (size_t)(m0 + row) * K + k0 + c * 8);
      *(bf16x8*)(As + row * 72 + c * 8) = va;
      bf16x8 vb = *(const bf16x8*)(W + (size_t)(n0 + row) * K + k0 + c * 8);
      *(bf16x8*)(Bs + row * 72 + c * 8) = vb;
    }
    __syncthreads();
    #pragma unroll
    for (int kk = 0; kk < 2; kk++) {
      bf16x8 a[4], b[4];
      #pragma unroll
      for (int mt = 0; mt < 4; mt++)
        a[mt] = *(const bf16x8*)(As + (wm + mt * 16 + lr) * 72 + kk * 32 + q * 8);
      #pragma unroll
      for (int nt = 0; nt < 4; nt++)
        b[nt] = *(const bf16x8*)(Bs + (wn + nt * 16 + lr) * 72 + kk * 32 + q * 8);
      #pragma unroll
      for (int mt = 0; mt < 4; mt++)
        #pragma unroll
        for (int nt = 0; nt < 4; nt++)
          acc[mt][nt] = mfma16(a[mt], b[nt], acc[mt][nt]);
    }
    __syncthreads();
  }
  #pragma unroll
  for (int mt = 0; mt < 4; mt++)
    #pragma unroll
    for (int nt = 0; nt < 4; nt++)
      #pragma unroll
      for (int r = 0; r < 4; r++) {
        int row = m0 + wm + mt * 16 + q * 4 + r;
        int col = n0 + wn + nt * 16 + lr;
        if (col < nvalid) {
          float v = acc[mt][nt][r] + bias[col];
          if (RELU) v = fmaxf(v, 0.f);
          if (PERM) row = ((row & 127) << 6) | (row >> 7);
          if (OUT_BF16)
            ((unsigned short*)Cout)[(size_t)row * ldc + col] = f2bf(v);
          else
            ((float*)Cout)[(size_t)row * ldc + col] = v;
        }
      }
}

// ---------------------------------------------------------------------------
// lstm_persist: PERSISTENT kernel -- all 129 phases in ONE launch.
//
// Round-2 post-mortem: agent-scope ATOMIC loads in the MFMA operand path
// serialized (compiler does not pipeline atomic loads; each pays ~900cy MALL
// latency, bypassing L2) -> 29.5 us/phase, MfmaUtil 2%. Fix this round:
//  - h uses PLAIN cached loads/stores (identical codegen to the verified
//    launch-based round-1 body: compiler-batched dwordx4 + fine waitcnt).
//  - coherence moves to the barrier only, mimicking a kernel boundary:
//      arrive:  fetch_add(bar, RELEASE, AGENT)  -> buffer_wbl2 (dirty h/lob
//               written back to MALL) before the counter bumps
//      depart:  spin relaxed; final ACQUIRE load -> buffer_inv (L0+L2 drop
//               stale h); subsequent plain loads refill fresh from MALL
//    Per-phase cost = L2 refill of weights+h (~24 MB agg @ MALL BW ~2us)
//    + barrier skew -- vs ~15 us of dispatch/drain per launch boundary.
//  - c1/c2 in registers (stable thread<->cell map across phases).
//  - co-residency by capacity: 256 blocks, LDS 34.8KB, 8 waves/block ->
//    >=1 block/CU on 256 CUs; bounded spin as fail-visible safety net.
// Work partition & math identical to verified round-1 lstm_phase.
//  Blocks 0..127   (A): layer-1 cell for t=p    (p<TT),  32 gate-cols
//  Blocks 128..255 (B): layer-2 cell for t=p-1  (p>0),   32 gate-cols
// hbuf = [2][64][2048] bf16 (h1|h2 halves):
//   A(p): reads hprev.h1 = h1(p-1); writes hc.h1 = h1(p).
//   B(p): reads hprev.h1, hc.h2 = h2(p-2); writes hprev.h2 = h2(p-1).
//   All same-phase read/write sets disjoint -> race-free.
// ---------------------------------------------------------------------------
__global__ __launch_bounds__(512) void lstm_persist(
    const unsigned short* __restrict__ Whh1b,   // [4096][1024]
    const unsigned short* __restrict__ W2cat,   // [4096][2048]
    const unsigned short* __restrict__ gxb,     // [T*64][4096] (t-major)
    const float* __restrict__ b2,
    unsigned short* __restrict__ hbuf,          // [2][64][2048]
    unsigned short* __restrict__ lob,           // [8192][1024]
    unsigned int* __restrict__ bar)
{
  __shared__ float red[4][64][34];   // [kq][row][grp0:0..15 | pad | grp1:17..32 | pad]
  const int t = threadIdx.x;
  const int w = t >> 6, lane = t & 63, lr = lane & 15, q = lane >> 4;
  const int kq = w & 3, rh = w >> 2;           // K-quarter, row-half
  const bool isA = (blockIdx.x < 128);
  const int j0 = (isA ? blockIdx.x : blockIdx.x - 128) * 8;
  const int g0 = lr >> 2, u0 = lr & 3;
  const int cm = t >> 3, cu = t & 7, ju = j0 + cu;
  const int cb = (cu >> 2) * 17 + (cu & 3);
  float creg = 0.f;                            // c1 (A) / c2 (B) cell state

  // phase-invariant weight pointers
  const unsigned short* wpA0 =
      Whh1b + (size_t)(g0 * 1024 + j0 + u0) * 1024 + kq * 256 + q * 8;
  const unsigned short* wpA1 = wpA0 + 4 * 1024;
  const unsigned short* wpB0 =
      W2cat + (size_t)(g0 * 1024 + j0 + u0) * 2048 + kq * 512 + q * 8;
  const unsigned short* wpB1 = wpB0 + 4 * 2048;

  for (int p = 0; p <= TT; p++) {
    const unsigned short* hprev = hbuf + (size_t)((p + 1) & 1) * 131072;
    unsigned short*       hc    = hbuf + (size_t)(p & 1) * 131072;

    if (isA) {
      if (p < TT) {
        const unsigned short* gp = gxb + ((size_t)(p << 6) + cm) * 4096 + ju;
        unsigned short gi = gp[0], gf = gp[1024], gg2 = gp[2048], go = gp[3072];
        {
          const int kof = kq * 256 + q * 8;
          const unsigned short* hb = hprev + (size_t)(rh * 32 + lr) * 2048 + kof;
          f32x4 acc[2][2] = {};
          #pragma unroll
          for (int ks = 0; ks < 8; ks++) {
            bf16x8 b0 = *(const bf16x8*)(wpA0 + ks * 32);
            bf16x8 b1 = *(const bf16x8*)(wpA1 + ks * 32);
            #pragma unroll
            for (int mt = 0; mt < 2; mt++) {
              bf16x8 af = *(const bf16x8*)(hb + (size_t)(mt * 16) * 2048 + ks * 32);
              acc[mt][0] = mfma16(af, b0, acc[mt][0]);
              acc[mt][1] = mfma16(af, b1, acc[mt][1]);
            }
          }
          #pragma unroll
          for (int mt = 0; mt < 2; mt++)
            #pragma unroll
            for (int r = 0; r < 4; r++) {
              red[kq][rh * 32 + mt * 16 + q * 4 + r][lr]      = acc[mt][0][r];
              red[kq][rh * 32 + mt * 16 + q * 4 + r][17 + lr] = acc[mt][1][r];
            }
        }
        __syncthreads();
        float s[4];
        #pragma unroll
        for (int gg = 0; gg < 4; gg++)
          s[gg] = red[0][cm][cb + gg * 4] + red[1][cm][cb + gg * 4]
                + red[2][cm][cb + gg * 4] + red[3][cm][cb + gg * 4];
        s[0] += bf2f(gi); s[1] += bf2f(gf); s[2] += bf2f(gg2); s[3] += bf2f(go);
        float i_ = sigmoidf_(s[0]), f_ = sigmoidf_(s[1]);
        float g_ = tanhf(s[2]), o_ = sigmoidf_(s[3]);
        float c = f_ * creg + i_ * g_;
        creg = c;
        hc[(size_t)cm * 2048 + ju] = f2bf(o_ * tanhf(c));
      }
    } else {
      if (p > 0) {
        {
          const int kof = kq * 512 + q * 8;
          // cols [0,1024) = h1(p-1) (hprev.h1); cols [1024,2048) = h2(p-2) (hc.h2)
          const unsigned short* hbase = (kq < 2) ? hprev : hc;
          const unsigned short* hb = hbase + (size_t)(rh * 32 + lr) * 2048 + kof;
          f32x4 acc[2][2] = {};
          #pragma unroll
          for (int ks = 0; ks < 16; ks++) {
            bf16x8 b0 = *(const bf16x8*)(wpB0 + ks * 32);
            bf16x8 b1 = *(const bf16x8*)(wpB1 + ks * 32);
            #pragma unroll
            for (int mt = 0; mt < 2; mt++) {
              bf16x8 af = *(const bf16x8*)(hb + (size_t)(mt * 16) * 2048 + ks * 32);
              acc[mt][0] = mfma16(af, b0, acc[mt][0]);
              acc[mt][1] = mfma16(af, b1, acc[mt][1]);
            }
          }
          #pragma unroll
          for (int mt = 0; mt < 2; mt++)
            #pragma unroll
            for (int r = 0; r < 4; r++) {
              red[kq][rh * 32 + mt * 16 + q * 4 + r][lr]      = acc[mt][0][r];
              red[kq][rh * 32 + mt * 16 + q * 4 + r][17 + lr] = acc[mt][1][r];
            }
        }
        __syncthreads();
        float s[4];
        #pragma unroll
        for (int gg = 0; gg < 4; gg++)
          s[gg] = red[0][cm][cb + gg * 4] + red[1][cm][cb + gg * 4]
                + red[2][cm][cb + gg * 4] + red[3][cm][cb + gg * 4]
                + b2[gg * 1024 + ju];
        float i_ = sigmoidf_(s[0]), f_ = sigmoidf_(s[1]);
        float g_ = tanhf(s[2]), o_ = sigmoidf_(s[3]);
        float c = f_ * creg + i_ * g_;
        creg = c;
        float h2v = o_ * tanhf(c);
        ((unsigned short*)hprev)[(size_t)cm * 2048 + 1024 + ju] = f2bf(h2v);
        float h1v = bf2f(hprev[(size_t)cm * 2048 + ju]);   // h1(p-1)
        lob[((size_t)(cm << 7) + (p - 1)) * 1024 + ju] = f2bf(h1v + h2v);
      }
    }

    // ---- device-wide phase barrier with kernel-boundary coherence ----
    if (p < TT) {
      __syncthreads();   // all waves' stores drained into L2 (vmcnt0+s_barrier)
      if (t == 0) {
        // RELEASE: buffer_wbl2 (dirty L2 -> MALL) precedes the counter bump
        __hip_atomic_fetch_add(bar, 1u, __ATOMIC_RELEASE, __HIP_MEMORY_SCOPE_AGENT);
        const unsigned tgt = 256u * (unsigned)(p + 1);
        unsigned iters = 0;
        while (__hip_atomic_load(bar, __ATOMIC_RELAXED, __HIP_MEMORY_SCOPE_AGENT) < tgt) {
          __builtin_amdgcn_s_sleep(2);
          if (++iters > 100000000u) break;   // fail-visible, never hang
        }
        // ACQUIRE: buffer_inv (drop stale L0/L2) before next phase's loads
        (void)__hip_atomic_load(bar, __ATOMIC_ACQUIRE, __HIP_MEMORY_SCOPE_AGENT);
      }
      __syncthreads();
    }
  }
}

// ---------------------------------------------------------------------------
__global__ __launch_bounds__(256) void softmax_k(float* __restrict__ out)
{
  __shared__ float smax[4];
  __shared__ float ssum[4];
  const int m = blockIdx.x;
  const int t = threadIdx.x;
  const int lane = t & 63, wid = t >> 6;
  const bool act = (t < 250);
  float x[4] = {0.f, 0.f, 0.f, 0.f};
  if (act) *(float4*)x = *(const float4*)(out + (size_t)m * NANS + t * 4);
  float v = act ? fmaxf(fmaxf(x[0], x[1]), fmaxf(x[2], x[3])) : -1e30f;
  #pragma unroll
  for (int o = 32; o > 0; o >>= 1) v = fmaxf(v, __shfl_down(v, o));
  if (lane == 0) smax[wid] = v;
  __syncthreads();
  const float mx = fmaxf(fmaxf(smax[0], smax[1]), fmaxf(smax[2], smax[3]));
  float e[4] = {0.f, 0.f, 0.f, 0.f};
  float s = 0.f;
  if (act) {
    e[0] = expf(x[0] - mx); e[1] = expf(x[1] - mx);
    e[2] = expf(x[2] - mx); e[3] = expf(x[3] - mx);
    s = (e[0] + e[1]) + (e[2] + e[3]);
  }
  #pragma unroll
  for (int o = 32; o > 0; o >>= 1) s += __shfl_down(s, o);
  if (lane == 0) ssum[wid] = s;
  __syncthreads();
  const float inv = 1.0f / (((ssum[0] + ssum[1]) + (ssum[2] + ssum[3])));
  if (act) {
    float4 o4 = make_float4(e[0] * inv, e[1] * inv, e[2] * inv, e[3] * inv);
    *(float4*)(out + (size_t)m * NANS + t * 4) = o4;
  }
}

// ---------------------------------------------------------------------------
extern "C" void kernel_launch(void* const* d_in, const int* in_sizes, int n_in,
                              void* d_out, int out_size, void* d_ws, size_t ws_size,
                              hipStream_t stream)
{
  const float* d1   = (const float*)d_in[0];
  const float* d2   = (const float*)d_in[1];
  const float* Wih1 = (const float*)d_in[2];
  const float* Whh1 = (const float*)d_in[3];
  const float* b1   = (const float*)d_in[4];
  const float* Wih2 = (const float*)d_in[5];
  const float* Whh2 = (const float*)d_in[6];
  const float* b2   = (const float*)d_in[7];
  const float* Wp1  = (const float*)d_in[8];
  const float* bp1  = (const float*)d_in[9];
  const float* Wp2  = (const float*)d_in[10];
  const float* bp2  = (const float*)d_in[11];
  float* out = (float*)d_out;

  // workspace layout (bytes)
  unsigned char* p = (unsigned char*)d_ws;
  unsigned short* gxb   = (unsigned short*)p;  p += 67108864;  // [T*64][4096]
  unsigned short* jb    = (unsigned short*)p;  p += 33554432;  // [8192][2048]
  unsigned short* Wb1   = (unsigned short*)p;  p += 16777216;  // [4096][2048]
  unsigned short* W2cat = (unsigned short*)p;  p += 16777216;  // [4096][2048]
  unsigned short* Whh1b = (unsigned short*)p;  p += 8388608;   // [4096][1024]
  unsigned short* lob   = (unsigned short*)p;  p += 16777216;  // [8192][1024]
  unsigned short* hidb  = (unsigned short*)p;  p += 4194304;   // [8192][256]
  unsigned short* Wp1t  = (unsigned short*)p;  p += 524288;    // [256][1024]
  unsigned short* Wp2t  = (unsigned short*)p;  p += 524288;    // [1024][256]
  unsigned short* hbuf  = (unsigned short*)p;  p += 524288;    // [2][64][2048]
  unsigned int*   bar   = (unsigned int*)p;    p += 256;       // phase barrier
  if (ws_size < (size_t)(p - (unsigned char*)d_ws)) return;

  // ---- convert inputs/weights to bf16 ----
  concat_cast<<<16384, 256, 0, stream>>>(d1, d2, jb, 11, 16777216L);
  cast_bf16<<<8192, 256, 0, stream>>>(Wih1, Wb1, 8388608L);
  cast_bf16<<<4096, 256, 0, stream>>>(Whh1, Whh1b, 4194304L);
  concat_cast<<<8192, 256, 0, stream>>>(Wih2, Whh2, W2cat, 11, 8388608L);
  cvt_wp1<<<1024, 256, 0, stream>>>(Wp1, Wp1t);
  cvt_wp2<<<1024, 256, 0, stream>>>(Wp2, Wp2t);
  zero_hb<<<128, 256, 0, stream>>>((float4*)hbuf, bar);   // hbuf (512 KiB) + bar

  // ---- gx = joint @ Wih1^T + b1 (t-major permuted, bf16) ----
  mfma_gemm<1, 0, 1><<<dim3(32, 64), 256, 0, stream>>>(
      jb, Wb1, b1, gxb, MALL, G4, DIN, G4, G4);

  // ---- recurrent loop: ONE persistent launch, fence-based phase barrier ----
  lstm_persist<<<256, 512, 0, stream>>>(Whh1b, W2cat, gxb, b2, hbuf, lob, bar);

  // ---- predict MLP + softmax ----
  mfma_gemm<1, 1, 0><<<dim3(2, 64), 256, 0, stream>>>(
      lob, Wp1t, bp1, hidb, MALL, 256, 1024, 256, 256);
  mfma_gemm<0, 0, 0><<<dim3(8, 64), 256, 0, stream>>>(
      hidb, Wp2t, bp2, out, MALL, 1024, 256, NANS, NANS);
  softmax_k<<<MALL, 256, 0, stream>>>(out);
}

// Round 4
// 3138.121 us; speedup vs baseline: 1.5491x; 1.5491x over previous
//
#include <hip/hip_runtime.h>
#include <math.h>

#define BB   64
#define TT   128
#define HH   1024
#define DIN  2048
#define G4   4096
#define MALL 8192   // B*T
#define NANS 1000

typedef __attribute__((ext_vector_type(8))) short bf16x8;
typedef __attribute__((ext_vector_type(4))) float f32x4;

__device__ __forceinline__ float sigmoidf_(float x) { return 1.0f / (1.0f + expf(-x)); }

__device__ __forceinline__ unsigned short f2bf(float f) {
  unsigned u = __float_as_uint(f);
  u = (u + 0x7fff + ((u >> 16) & 1)) >> 16;   // RNE
  return (unsigned short)u;
}
__device__ __forceinline__ float bf2f(unsigned short h) {
  return __uint_as_float(((unsigned)h) << 16);
}
__device__ __forceinline__ f32x4 mfma16(bf16x8 a, bf16x8 b, f32x4 c) {
  return __builtin_amdgcn_mfma_f32_16x16x32_bf16(a, b, c, 0, 0, 0);
}

// --- MALL-coherent h path -------------------------------------------------
// hbuf NEVER enters any L2: all writes are sc1 write-through (atomic store),
// all reads are sc0+sc1 loads (bypass L0/L2, read MALL). So no wbl2/inv is
// needed anywhere and weights stay warm in per-XCD L2 across all phases.
// Reads use inline-asm plain VMEM loads so they PIPELINE (round-2 lesson:
// compiler schedules atomic loads at use-site -> ~900cy exposed per load).
__device__ __forceinline__ void ldg_b128_sys(bf16x8* d, const unsigned short* p) {
  asm volatile("global_load_dwordx4 %0, %1, off sc0 sc1" : "=v"(*d) : "v"(p));
}
__device__ __forceinline__ void ldg_u16_sys(unsigned* d, const unsigned short* p) {
  asm volatile("global_load_ushort %0, %1, off sc0 sc1" : "=v"(*d) : "v"(p));
}
// rule #18: single drain + sched fence before consuming asm-loaded regs
#define VMEM_FENCE() do { \
  asm volatile("s_waitcnt vmcnt(0)" ::: "memory"); \
  __builtin_amdgcn_sched_barrier(0); \
} while (0)

__device__ __forceinline__ void st_h2(unsigned short* p, unsigned short v) {
  __hip_atomic_store(p, v, __ATOMIC_RELAXED, __HIP_MEMORY_SCOPE_AGENT);
}

// ---------------------------------------------------------------------------
// conversion kernels
// ---------------------------------------------------------------------------
__global__ __launch_bounds__(256) void concat_cast(
    const float* __restrict__ a, const float* __restrict__ b,
    unsigned short* __restrict__ o, int rshift, long total)
{
  long idx = ((long)blockIdx.x * 256 + threadIdx.x) * 4;
  if (idx >= total) return;
  int row = (int)(idx >> rshift);
  int col = (int)(idx & ((1L << rshift) - 1));
  int half = 1 << (rshift - 1);
  const float* s = (col < half) ? (a + (size_t)row * half + col)
                                : (b + (size_t)row * half + col - half);
  float4 v = *(const float4*)s;
  ushort4 ov;
  ov.x = f2bf(v.x); ov.y = f2bf(v.y); ov.z = f2bf(v.z); ov.w = f2bf(v.w);
  *(ushort4*)(o + idx) = ov;
}

__global__ __launch_bounds__(256) void cast_bf16(
    const float* __restrict__ s, unsigned short* __restrict__ o, long n)
{
  long idx = ((long)blockIdx.x * 256 + threadIdx.x) * 4;
  if (idx >= n) return;
  float4 v = *(const float4*)(s + idx);
  ushort4 ov;
  ov.x = f2bf(v.x); ov.y = f2bf(v.y); ov.z = f2bf(v.z); ov.w = f2bf(v.w);
  *(ushort4*)(o + idx) = ov;
}

__global__ __launch_bounds__(256) void cvt_wp1(
    const float* __restrict__ Wp1, unsigned short* __restrict__ o)
{
  int idx = blockIdx.x * 256 + threadIdx.x;    // 262144
  int n = idx >> 10, k = idx & 1023;
  o[idx] = f2bf(Wp1[(size_t)k * 256 + n]);
}

__global__ __launch_bounds__(256) void cvt_wp2(
    const float* __restrict__ Wp2, unsigned short* __restrict__ o)
{
  int idx = blockIdx.x * 256 + threadIdx.x;    // 262144
  int n = idx >> 8, k = idx & 255;
  o[idx] = f2bf(n < NANS ? Wp2[(size_t)k * NANS + n] : 0.f);
}

__global__ __launch_bounds__(256) void zero_hb(
    float4* __restrict__ p, unsigned int* __restrict__ bar)
{
  p[blockIdx.x * 256 + threadIdx.x] = make_float4(0.f, 0.f, 0.f, 0.f);
  if (blockIdx.x == 0 && threadIdx.x == 0) *bar = 0u;
}

// ---------------------------------------------------------------------------
// Templated bf16 MFMA GEMM: C = A @ W^T (+bias)(relu). 128x128 tile, BK=64.
// ---------------------------------------------------------------------------
template<int OUT_BF16, int RELU, int PERM>
__global__ __launch_bounds__(256) void mfma_gemm(
    const unsigned short* __restrict__ A,   // [M][K] bf16
    const unsigned short* __restrict__ W,   // [N][K] bf16
    const float* __restrict__ bias,         // [nvalid]
    void* __restrict__ Cout,
    int M, int N, int K, int ldc, int nvalid)
{
  __shared__ __align__(16) unsigned short As[128 * 72];
  __shared__ __align__(16) unsigned short Bs[128 * 72];
  const int t = threadIdx.x;
  const int n0 = blockIdx.x * 128, m0 = blockIdx.y * 128;
  const int w = t >> 6, lane = t & 63, lr = lane & 15, q = lane >> 4;
  const int wn = (w & 1) * 64, wm = (w >> 1) * 64;
  f32x4 acc[4][4] = {};
  for (int k0 = 0; k0 < K; k0 += 64) {
    #pragma unroll
    for (int s = 0; s < 4; s++) {
      int ci = s * 256 + t;
      int row = ci >> 3, c = ci & 7;
      bf16x8 va = *(const bf16x8*)(A + (size_t)(m0 + row) * K + k0 + c * 8);
      *(bf16x8*)(As + row * 72 + c * 8) = va;
      bf16x8 vb = *(const bf16x8*)(W + (size_t)(n0 + row) * K + k0 + c * 8);
      *(bf16x8*)(Bs + row * 72 + c * 8) = vb;
    }
    __syncthreads();
    #pragma unroll
    for (int kk = 0; kk < 2; kk++) {
      bf16x8 a[4], b[4];
      #pragma unroll
      for (int mt = 0; mt < 4; mt++)
        a[mt] = *(const bf16x8*)(As + (wm + mt * 16 + lr) * 72 + kk * 32 + q * 8);
      #pragma unroll
      for (int nt = 0; nt < 4; nt++)
        b[nt] = *(const bf16x8*)(Bs + (wn + nt * 16 + lr) * 72 + kk * 32 + q * 8);
      #pragma unroll
      for (int mt = 0; mt < 4; mt++)
        #pragma unroll
        for (int nt = 0; nt < 4; nt++)
          acc[mt][nt] = mfma16(a[mt], b[nt], acc[mt][nt]);
    }
    __syncthreads();
  }
  #pragma unroll
  for (int mt = 0; mt < 4; mt++)
    #pragma unroll
    for (int nt = 0; nt < 4; nt++)
      #pragma unroll
      for (int r = 0; r < 4; r++) {
        int row = m0 + wm + mt * 16 + q * 4 + r;
        int col = n0 + wn + nt * 16 + lr;
        if (col < nvalid) {
          float v = acc[mt][nt][r] + bias[col];
          if (RELU) v = fmaxf(v, 0.f);
          if (PERM) row = ((row & 127) << 6) | (row >> 7);
          if (OUT_BF16)
            ((unsigned short*)Cout)[(size_t)row * ldc + col] = f2bf(v);
          else
            ((float*)Cout)[(size_t)row * ldc + col] = v;
        }
      }
}

// ---------------------------------------------------------------------------
// lstm_persist: PERSISTENT kernel -- all 129 phases in ONE launch.
//
// Round-2 post-mortem: barrier fine; atomic h LOADS scheduled at use-site ->
// ~16x900cy exposed MALL latency per wave -> 29.5us/phase.
// Round-3 post-mortem: per-block REL/ACQ wbl2+inv killed L2 weight residency
// -> 35us/phase. BOTH coherence schemes that touch L2 are dead ends.
// This round: hbuf lives ONLY in MALL (sc1 write-through stores + sc0 sc1
// asm loads), so no cache maintenance exists anywhere; the asm loads are
// BATCH-issued (32 in flight) with ONE vmcnt(0) drain -> MALL latency paid
// once per phase, not 16x. Weights/gxb/b2 stay plain L2-cached (warm all
// 128 phases). Barrier: relaxed monotonic counter (verified round 2).
// __launch_bounds__(512,2): cap 256 VGPR (B-side holds 128 VGPR of h regs).
// Work partition & math identical to verified rounds 1-3.
//  Blocks 0..127   (A): layer-1 cell for t=p    (p<TT),  32 gate-cols
//  Blocks 128..255 (B): layer-2 cell for t=p-1  (p>0),   32 gate-cols
// hbuf = [2][64][2048] bf16 (h1|h2 halves):
//   A(p): reads hprev.h1 = h1(p-1); writes hc.h1 = h1(p).
//   B(p): reads hprev.h1, hc.h2 = h2(p-2); writes hprev.h2 = h2(p-1).
//   All same-phase read/write sets disjoint -> race-free.
// Visibility: __syncthreads drains vmcnt(0) (sc1 stores ack at MALL) before
// thread-0's counter bump; consumers observe counter then sc1-read MALL.
// ---------------------------------------------------------------------------
__global__ __launch_bounds__(512, 2) void lstm_persist(
    const unsigned short* __restrict__ Whh1b,   // [4096][1024]
    const unsigned short* __restrict__ W2cat,   // [4096][2048]
    const unsigned short* __restrict__ gxb,     // [T*64][4096] (t-major)
    const float* __restrict__ b2,
    unsigned short* __restrict__ hbuf,          // [2][64][2048]
    unsigned short* __restrict__ lob,           // [8192][1024]
    unsigned int* __restrict__ bar)
{
  __shared__ float red[4][64][34];   // [kq][row][grp0:0..15 | pad | grp1:17..32 | pad]
  const int t = threadIdx.x;
  const int w = t >> 6, lane = t & 63, lr = lane & 15, q = lane >> 4;
  const int kq = w & 3, rh = w >> 2;           // K-quarter, row-half
  const bool isA = (blockIdx.x < 128);
  const int j0 = (isA ? blockIdx.x : blockIdx.x - 128) * 8;
  const int g0 = lr >> 2, u0 = lr & 3;
  const int cm = t >> 3, cu = t & 7, ju = j0 + cu;
  const int cb = (cu >> 2) * 17 + (cu & 3);
  float creg = 0.f;                            // c1 (A) / c2 (B) cell state

  // phase-invariant weight pointers (plain cached -> L2-resident all phases)
  const unsigned short* wpA0 =
      Whh1b + (size_t)(g0 * 1024 + j0 + u0) * 1024 + kq * 256 + q * 8;
  const unsigned short* wpA1 = wpA0 + 4 * 1024;
  const unsigned short* wpB0 =
      W2cat + (size_t)(g0 * 1024 + j0 + u0) * 2048 + kq * 512 + q * 8;
  const unsigned short* wpB1 = wpB0 + 4 * 2048;

  for (int p = 0; p <= TT; p++) {
    const unsigned short* hprev = hbuf + (size_t)((p + 1) & 1) * 131072;
    unsigned short*       hc    = hbuf + (size_t)(p & 1) * 131072;

    if (isA) {
      if (p < TT) {
        const unsigned short* gp = gxb + ((size_t)(p << 6) + cm) * 4096 + ju;
        unsigned short gi = gp[0], gf = gp[1024], gg2 = gp[2048], go = gp[3072];
        // ---- batched h1(p-1) prefetch: 16 pipelined MALL loads ----
        bf16x8 hreg[16];
        {
          const int kof = kq * 256 + q * 8;
          const unsigned short* hb = hprev + (size_t)(rh * 32 + lr) * 2048 + kof;
          #pragma unroll
          for (int ks = 0; ks < 8; ks++) {
            ldg_b128_sys(&hreg[2 * ks],     hb + ks * 32);
            ldg_b128_sys(&hreg[2 * ks + 1], hb + 16 * 2048 + ks * 32);
          }
        }
        VMEM_FENCE();
        {
          f32x4 acc[2][2] = {};
          #pragma unroll
          for (int ks = 0; ks < 8; ks++) {
            bf16x8 b0 = *(const bf16x8*)(wpA0 + ks * 32);
            bf16x8 b1 = *(const bf16x8*)(wpA1 + ks * 32);
            acc[0][0] = mfma16(hreg[2 * ks],     b0, acc[0][0]);
            acc[0][1] = mfma16(hreg[2 * ks],     b1, acc[0][1]);
            acc[1][0] = mfma16(hreg[2 * ks + 1], b0, acc[1][0]);
            acc[1][1] = mfma16(hreg[2 * ks + 1], b1, acc[1][1]);
          }
          #pragma unroll
          for (int mt = 0; mt < 2; mt++)
            #pragma unroll
            for (int r = 0; r < 4; r++) {
              red[kq][rh * 32 + mt * 16 + q * 4 + r][lr]      = acc[mt][0][r];
              red[kq][rh * 32 + mt * 16 + q * 4 + r][17 + lr] = acc[mt][1][r];
            }
        }
        __syncthreads();
        float s[4];
        #pragma unroll
        for (int gg = 0; gg < 4; gg++)
          s[gg] = red[0][cm][cb + gg * 4] + red[1][cm][cb + gg * 4]
                + red[2][cm][cb + gg * 4] + red[3][cm][cb + gg * 4];
        s[0] += bf2f(gi); s[1] += bf2f(gf); s[2] += bf2f(gg2); s[3] += bf2f(go);
        float i_ = sigmoidf_(s[0]), f_ = sigmoidf_(s[1]);
        float g_ = tanhf(s[2]), o_ = sigmoidf_(s[3]);
        float c = f_ * creg + i_ * g_;
        creg = c;
        st_h2(hc + (size_t)cm * 2048 + ju, f2bf(o_ * tanhf(c)));
      }
    } else {
      if (p > 0) {
        // ---- batched h prefetch: 32 pipelined MALL loads + h1 scalar ----
        bf16x8 hreg[32];
        unsigned h1raw;
        {
          const int kof = kq * 512 + q * 8;
          // cols [0,1024) = h1(p-1) (hprev.h1); cols [1024,2048) = h2(p-2) (hc.h2)
          const unsigned short* hbase = (kq < 2) ? hprev : hc;
          const unsigned short* hb = hbase + (size_t)(rh * 32 + lr) * 2048 + kof;
          #pragma unroll
          for (int ks = 0; ks < 16; ks++) {
            ldg_b128_sys(&hreg[2 * ks],     hb + ks * 32);
            ldg_b128_sys(&hreg[2 * ks + 1], hb + 16 * 2048 + ks * 32);
          }
          ldg_u16_sys(&h1raw, hprev + (size_t)cm * 2048 + ju);
        }
        VMEM_FENCE();
        {
          f32x4 acc[2][2] = {};
          #pragma unroll
          for (int ks = 0; ks < 16; ks++) {
            bf16x8 b0 = *(const bf16x8*)(wpB0 + ks * 32);
            bf16x8 b1 = *(const bf16x8*)(wpB1 + ks * 32);
            acc[0][0] = mfma16(hreg[2 * ks],     b0, acc[0][0]);
            acc[0][1] = mfma16(hreg[2 * ks],     b1, acc[0][1]);
            acc[1][0] = mfma16(hreg[2 * ks + 1], b0, acc[1][0]);
            acc[1][1] = mfma16(hreg[2 * ks + 1], b1, acc[1][1]);
          }
          #pragma unroll
          for (int mt = 0; mt < 2; mt++)
            #pragma unroll
            for (int r = 0; r < 4; r++) {
              red[kq][rh * 32 + mt * 16 + q * 4 + r][lr]      = acc[mt][0][r];
              red[kq][rh * 32 + mt * 16 + q * 4 + r][17 + lr] = acc[mt][1][r];
            }
        }
        __syncthreads();
        float s[4];
        #pragma unroll
        for (int gg = 0; gg < 4; gg++)
          s[gg] = red[0][cm][cb + gg * 4] + red[1][cm][cb + gg * 4]
                + red[2][cm][cb + gg * 4] + red[3][cm][cb + gg * 4]
                + b2[gg * 1024 + ju];
        float i_ = sigmoidf_(s[0]), f_ = sigmoidf_(s[1]);
        float g_ = tanhf(s[2]), o_ = sigmoidf_(s[3]);
        float c = f_ * creg + i_ * g_;
        creg = c;
        float h2v = o_ * tanhf(c);
        st_h2((unsigned short*)hprev + (size_t)cm * 2048 + 1024 + ju, f2bf(h2v));
        float h1v = bf2f((unsigned short)h1raw);           // h1(p-1), prefetched
        lob[((size_t)(cm << 7) + (p - 1)) * 1024 + ju] = f2bf(h1v + h2v);
      }
    }

    // ---- device-wide phase barrier (relaxed counter; no cache maintenance) ----
    if (p < TT) {
      __syncthreads();   // vmcnt(0) drain: sc1 h-stores ack'd at MALL
      if (t == 0) {
        __hip_atomic_fetch_add(bar, 1u, __ATOMIC_RELAXED, __HIP_MEMORY_SCOPE_AGENT);
        const unsigned tgt = 256u * (unsigned)(p + 1);
        unsigned iters = 0;
        while (__hip_atomic_load(bar, __ATOMIC_RELAXED, __HIP_MEMORY_SCOPE_AGENT) < tgt) {
          __builtin_amdgcn_s_sleep(2);
          if (++iters > 100000000u) break;   // fail-visible, never hang
        }
      }
      __syncthreads();
    }
  }
}

// ---------------------------------------------------------------------------
__global__ __launch_bounds__(256) void softmax_k(float* __restrict__ out)
{
  __shared__ float smax[4];
  __shared__ float ssum[4];
  const int m = blockIdx.x;
  const int t = threadIdx.x;
  const int lane = t & 63, wid = t >> 6;
  const bool act = (t < 250);
  float x[4] = {0.f, 0.f, 0.f, 0.f};
  if (act) *(float4*)x = *(const float4*)(out + (size_t)m * NANS + t * 4);
  float v = act ? fmaxf(fmaxf(x[0], x[1]), fmaxf(x[2], x[3])) : -1e30f;
  #pragma unroll
  for (int o = 32; o > 0; o >>= 1) v = fmaxf(v, __shfl_down(v, o));
  if (lane == 0) smax[wid] = v;
  __syncthreads();
  const float mx = fmaxf(fmaxf(smax[0], smax[1]), fmaxf(smax[2], smax[3]));
  float e[4] = {0.f, 0.f, 0.f, 0.f};
  float s = 0.f;
  if (act) {
    e[0] = expf(x[0] - mx); e[1] = expf(x[1] - mx);
    e[2] = expf(x[2] - mx); e[3] = expf(x[3] - mx);
    s = (e[0] + e[1]) + (e[2] + e[3]);
  }
  #pragma unroll
  for (int o = 32; o > 0; o >>= 1) s += __shfl_down(s, o);
  if (lane == 0) ssum[wid] = s;
  __syncthreads();
  const float inv = 1.0f / (((ssum[0] + ssum[1]) + (ssum[2] + ssum[3])));
  if (act) {
    float4 o4 = make_float4(e[0] * inv, e[1] * inv, e[2] * inv, e[3] * inv);
    *(float4*)(out + (size_t)m * NANS + t * 4) = o4;
  }
}

// ---------------------------------------------------------------------------
extern "C" void kernel_launch(void* const* d_in, const int* in_sizes, int n_in,
                              void* d_out, int out_size, void* d_ws, size_t ws_size,
                              hipStream_t stream)
{
  const float* d1   = (const float*)d_in[0];
  const float* d2   = (const float*)d_in[1];
  const float* Wih1 = (const float*)d_in[2];
  const float* Whh1 = (const float*)d_in[3];
  const float* b1   = (const float*)d_in[4];
  const float* Wih2 = (const float*)d_in[5];
  const float* Whh2 = (const float*)d_in[6];
  const float* b2   = (const float*)d_in[7];
  const float* Wp1  = (const float*)d_in[8];
  const float* bp1  = (const float*)d_in[9];
  const float* Wp2  = (const float*)d_in[10];
  const float* bp2  = (const float*)d_in[11];
  float* out = (float*)d_out;

  // workspace layout (bytes)
  unsigned char* p = (unsigned char*)d_ws;
  unsigned short* gxb   = (unsigned short*)p;  p += 67108864;  // [T*64][4096]
  unsigned short* jb    = (unsigned short*)p;  p += 33554432;  // [8192][2048]
  unsigned short* Wb1   = (unsigned short*)p;  p += 16777216;  // [4096][2048]
  unsigned short* W2cat = (unsigned short*)p;  p += 16777216;  // [4096][2048]
  unsigned short* Whh1b = (unsigned short*)p;  p += 8388608;   // [4096][1024]
  unsigned short* lob   = (unsigned short*)p;  p += 16777216;  // [8192][1024]
  unsigned short* hidb  = (unsigned short*)p;  p += 4194304;   // [8192][256]
  unsigned short* Wp1t  = (unsigned short*)p;  p += 524288;    // [256][1024]
  unsigned short* Wp2t  = (unsigned short*)p;  p += 524288;    // [1024][256]
  unsigned short* hbuf  = (unsigned short*)p;  p += 524288;    // [2][64][2048]
  unsigned int*   bar   = (unsigned int*)p;    p += 256;       // phase barrier
  if (ws_size < (size_t)(p - (unsigned char*)d_ws)) return;

  // ---- convert inputs/weights to bf16 ----
  concat_cast<<<16384, 256, 0, stream>>>(d1, d2, jb, 11, 16777216L);
  cast_bf16<<<8192, 256, 0, stream>>>(Wih1, Wb1, 8388608L);
  cast_bf16<<<4096, 256, 0, stream>>>(Whh1, Whh1b, 4194304L);
  concat_cast<<<8192, 256, 0, stream>>>(Wih2, Whh2, W2cat, 11, 8388608L);
  cvt_wp1<<<1024, 256, 0, stream>>>(Wp1, Wp1t);
  cvt_wp2<<<1024, 256, 0, stream>>>(Wp2, Wp2t);
  zero_hb<<<128, 256, 0, stream>>>((float4*)hbuf, bar);   // hbuf (512 KiB) + bar

  // ---- gx = joint @ Wih1^T + b1 (t-major permuted, bf16) ----
  mfma_gemm<1, 0, 1><<<dim3(32, 64), 256, 0, stream>>>(
      jb, Wb1, b1, gxb, MALL, G4, DIN, G4, G4);

  // ---- recurrent loop: ONE persistent launch, MALL-resident h exchange ----
  lstm_persist<<<256, 512, 0, stream>>>(Whh1b, W2cat, gxb, b2, hbuf, lob, bar);

  // ---- predict MLP + softmax ----
  mfma_gemm<1, 1, 0><<<dim3(2, 64), 256, 0, stream>>>(
      lob, Wp1t, bp1, hidb, MALL, 256, 1024, 256, 256);
  mfma_gemm<0, 0, 0><<<dim3(8, 64), 256, 0, stream>>>(
      hidb, Wp2t, bp2, out, MALL, 1024, 256, NANS, NANS);
  softmax_k<<<MALL, 256, 0, stream>>>(out);
}